// Round 1
// baseline (266.962 us; speedup 1.0000x reference)
//
#include <hip/hip_runtime.h>
#include <hip/hip_bf16.h>
#include <stdint.h>

typedef __bf16 bf16_t;
typedef __attribute__((ext_vector_type(8))) __bf16 bf16x8;
typedef __attribute__((ext_vector_type(4))) __bf16 bf16x4;
typedef __attribute__((ext_vector_type(4))) float f32x4;

static constexpr int T_SEQ = 2048;
static constexpr int HID   = 2048;
static constexpr int NHEAD = 32;
static constexpr int NKVH  = 8;
static constexpr int HDIM  = 64;
static constexpr int QKVD  = 3072;   // 64*(32+16)

__device__ inline f32x4 mfma16(bf16x8 a, bf16x8 b, f32x4 c) {
    return __builtin_amdgcn_mfma_f32_16x16x32_bf16(a, b, c, 0, 0, 0);
}

// ---------------- transpose + cast: in fp32 [K][N] -> out bf16 [N][K] ----------------
__global__ __launch_bounds__(256) void transpose_cast(const float* __restrict__ in,
                                                      bf16_t* __restrict__ out,
                                                      int K, int N) {
    __shared__ float tile[32][33];
    int tx = threadIdx.x & 31, ty = threadIdx.x >> 5;   // 32 x 8
    int bx = blockIdx.x, by = blockIdx.y;               // N/32, K/32
#pragma unroll
    for (int i = 0; i < 4; ++i)
        tile[ty + 8*i][tx] = in[(size_t)(by*32 + ty + 8*i)*N + bx*32 + tx];
    __syncthreads();
#pragma unroll
    for (int i = 0; i < 4; ++i)
        out[(size_t)(bx*32 + ty + 8*i)*K + by*32 + tx] = (bf16_t)tile[tx][ty + 8*i];
}

// ---------------- RMSNorm + cast to bf16 ----------------
__global__ __launch_bounds__(256) void rmsnorm_cast(const float* __restrict__ x,
                                                    const float* __restrict__ scale,
                                                    bf16_t* __restrict__ out) {
    int row = blockIdx.x;
    int tid = threadIdx.x;
    const float4* x4 = (const float4*)(x + (size_t)row * HID);
    const float4* s4 = (const float4*)scale;
    float4 v0 = x4[tid], v1 = x4[tid + 256];
    float ss = v0.x*v0.x + v0.y*v0.y + v0.z*v0.z + v0.w*v0.w
             + v1.x*v1.x + v1.y*v1.y + v1.z*v1.z + v1.w*v1.w;
#pragma unroll
    for (int off = 32; off > 0; off >>= 1) ss += __shfl_down(ss, off);
    __shared__ float wsum[4];
    if ((tid & 63) == 0) wsum[tid >> 6] = ss;
    __syncthreads();
    float total = wsum[0] + wsum[1] + wsum[2] + wsum[3];
    float inv = rsqrtf(total * (1.0f / HID) + 1e-5f);
    float4 sc0 = s4[tid], sc1 = s4[tid + 256];
    bf16_t* outr = out + (size_t)row * HID;
    bf16x4 o0, o1;
    o0.x = (bf16_t)(v0.x*inv*sc0.x); o0.y = (bf16_t)(v0.y*inv*sc0.y);
    o0.z = (bf16_t)(v0.z*inv*sc0.z); o0.w = (bf16_t)(v0.w*inv*sc0.w);
    o1.x = (bf16_t)(v1.x*inv*sc1.x); o1.y = (bf16_t)(v1.y*inv*sc1.y);
    o1.z = (bf16_t)(v1.z*inv*sc1.z); o1.w = (bf16_t)(v1.w*inv*sc1.w);
    *(bf16x4*)(outr + 4*tid)        = o0;
    *(bf16x4*)(outr + 1024 + 4*tid) = o1;
}

// ---------------- GEMM: C[M][N] = A[M][K](bf16) * Bt[N][K]^T(bf16) + bias (+resid) ----------------
template <int RES>
__global__ __launch_bounds__(256) void gemm_bt(const bf16_t* __restrict__ A,
                                               const bf16_t* __restrict__ Bt,
                                               const float* __restrict__ bias,
                                               const float* __restrict__ resid,
                                               float* __restrict__ C,
                                               int M, int N, int K) {
    __shared__ __align__(16) bf16_t Asm[128 * 40];   // pad 32 -> 40 (80B rows, 16B aligned)
    __shared__ __align__(16) bf16_t Bsm[128 * 40];
    const int tid = threadIdx.x;
    const int bm = blockIdx.y * 128, bn = blockIdx.x * 128;
    const int lane = tid & 63, wave = tid >> 6;
    const int wm = (wave & 1) * 64, wn = (wave >> 1) * 64;
    const int lm = lane & 15, quad = lane >> 4;

    f32x4 acc[4][4];
#pragma unroll
    for (int i = 0; i < 4; ++i)
#pragma unroll
        for (int j = 0; j < 4; ++j) acc[i][j] = (f32x4){0.f, 0.f, 0.f, 0.f};

    const int c0 = tid, c1 = tid + 256;
    const int r0 = c0 >> 2, kc0 = (c0 & 3) * 8;
    const int r1 = c1 >> 2, kc1 = (c1 & 3) * 8;

    for (int k0 = 0; k0 < K; k0 += 32) {
        uint4 a0 = *(const uint4*)(A  + (size_t)(bm + r0)*K + k0 + kc0);
        uint4 a1 = *(const uint4*)(A  + (size_t)(bm + r1)*K + k0 + kc1);
        uint4 b0 = *(const uint4*)(Bt + (size_t)(bn + r0)*K + k0 + kc0);
        uint4 b1 = *(const uint4*)(Bt + (size_t)(bn + r1)*K + k0 + kc1);
        *(uint4*)&Asm[r0*40 + kc0] = a0;
        *(uint4*)&Asm[r1*40 + kc1] = a1;
        *(uint4*)&Bsm[r0*40 + kc0] = b0;
        *(uint4*)&Bsm[r1*40 + kc1] = b1;
        __syncthreads();
        bf16x8 af[4], bfr[4];
#pragma unroll
        for (int i = 0; i < 4; ++i) af[i]  = *(const bf16x8*)&Asm[(wm + i*16 + lm)*40 + quad*8];
#pragma unroll
        for (int j = 0; j < 4; ++j) bfr[j] = *(const bf16x8*)&Bsm[(wn + j*16 + lm)*40 + quad*8];
#pragma unroll
        for (int i = 0; i < 4; ++i)
#pragma unroll
            for (int j = 0; j < 4; ++j) acc[i][j] = mfma16(af[i], bfr[j], acc[i][j]);
        __syncthreads();
    }

#pragma unroll
    for (int i = 0; i < 4; ++i) {
        int gr = bm + wm + i*16 + quad*4;
#pragma unroll
        for (int j = 0; j < 4; ++j) {
            int gc = bn + wn + j*16 + lm;
            float b = bias[gc];
#pragma unroll
            for (int r = 0; r < 4; ++r) {
                size_t idx = (size_t)(gr + r)*N + gc;
                float v = acc[i][j][r] + b;
                if (RES) v += resid[idx];
                C[idx] = v;
            }
        }
    }
}

// ---------------- RoPE (split-half) + cast, scatter into Q/K/V bf16 ----------------
__global__ __launch_bounds__(256) void rope_split(const float* __restrict__ qkv,
                                                  const float* __restrict__ cost,
                                                  const float* __restrict__ sint,
                                                  bf16_t* __restrict__ Qb,
                                                  bf16_t* __restrict__ Kb,
                                                  bf16_t* __restrict__ Vb) {
    int t = blockIdx.x;
    const float* row = qkv + (size_t)t * QKVD;
    const float* c = cost + (size_t)t * 32;
    const float* s = sint + (size_t)t * 32;
    for (int idx = threadIdx.x; idx < 1536; idx += 256) {
        int h = idx >> 5;     // 0..47 (32 q, 8 k, 8 v head-rows)
        int p = idx & 31;
        float x1 = row[h*64 + p], x2 = row[h*64 + p + 32];
        float o1, o2;
        if (h < 40) { float cc = c[p], ssn = s[p]; o1 = x1*cc - x2*ssn; o2 = x2*cc + x1*ssn; }
        else        { o1 = x1; o2 = x2; }
        bf16_t b1 = (bf16_t)o1, b2 = (bf16_t)o2;
        if (h < 32) {
            bf16_t* q = Qb + ((size_t)t*NHEAD + h)*HDIM;
            q[p] = b1; q[p + 32] = b2;
        } else if (h < 40) {
            bf16_t* k = Kb + ((size_t)t*NKVH + (h - 32))*HDIM;
            k[p] = b1; k[p + 32] = b2;
        } else {
            bf16_t* v = Vb + ((size_t)t*NKVH + (h - 40))*HDIM;
            v[p] = b1; v[p + 32] = b2;
        }
    }
}

// ---------------- attention: per (64-query tile, head); window fits one 192-key tile ----------------
__global__ __launch_bounds__(256) void attn_kernel(const bf16_t* __restrict__ Qb,
                                                   const bf16_t* __restrict__ Kb,
                                                   const bf16_t* __restrict__ Vb,
                                                   const float* __restrict__ sinks,
                                                   bf16_t* __restrict__ attnb) {
    // LDS plan (bytes): Qs[64][72] @0 (9216) ; Ks[192][72] @9216 (27648) ;
    //                   Vt[64][200] @36864 (25600) ; Ws[64][200] aliases @0 after sync.
    __shared__ __align__(16) char smem[62464];
    bf16_t* Qs = (bf16_t*)smem;
    bf16_t* Ks = (bf16_t*)(smem + 9216);
    bf16_t* Vt = (bf16_t*)(smem + 36864);
    bf16_t* Ws = (bf16_t*)smem;

    const int tid = threadIdx.x;
    const int qt = blockIdx.x, h = blockIdx.y;
    const int qs = qt * 64;
    const int nkv = h >> 2;

    // stage Q tile: 64 rows x 64 dims = 512 16B-chunks
#pragma unroll
    for (int it = 0; it < 2; ++it) {
        int cc = tid + it*256;
        int row = cc >> 3, off = (cc & 7) * 8;
        uint4 v = *(const uint4*)(Qb + ((size_t)(qs + row)*NHEAD + h)*HDIM + off);
        *(uint4*)&Qs[row*72 + off] = v;
    }
    // stage K (rows) and V (transposed) : 192 keys x 64 dims = 1536 chunks
#pragma unroll
    for (int it = 0; it < 6; ++it) {
        int cc = tid + it*256;
        int j = cc >> 3, off = (cc & 7) * 8;
        int kg = qs - 128 + j;
        uint4 kv = {0, 0, 0, 0}, vv = {0, 0, 0, 0};
        if (kg >= 0) {
            kv = *(const uint4*)(Kb + ((size_t)kg*NKVH + nkv)*HDIM + off);
            vv = *(const uint4*)(Vb + ((size_t)kg*NKVH + nkv)*HDIM + off);
        }
        *(uint4*)&Ks[j*72 + off] = kv;
        union { uint4 u; bf16_t e[8]; } uv; uv.u = vv;
#pragma unroll
        for (int r = 0; r < 8; ++r) Vt[(off + r)*200 + j] = uv.e[r];
    }
    __syncthreads();

    const int lane = tid & 63, wave = tid >> 6;
    const int lm = lane & 15, quad = lane >> 4;
    const int w16 = wave * 16;

    // S = Q K^T : each wave 16 queries x 192 keys
    f32x4 S[12];
#pragma unroll
    for (int jt = 0; jt < 12; ++jt) S[jt] = (f32x4){0.f, 0.f, 0.f, 0.f};
#pragma unroll
    for (int ks = 0; ks < 2; ++ks) {
        bf16x8 aq = *(const bf16x8*)&Qs[(w16 + lm)*72 + ks*32 + quad*8];
#pragma unroll
        for (int jt = 0; jt < 12; ++jt) {
            bf16x8 bk = *(const bf16x8*)&Ks[(jt*16 + lm)*72 + ks*32 + quad*8];
            S[jt] = mfma16(aq, bk, S[jt]);
        }
    }
    __syncthreads();   // all waves done reading Qs/Ks; Ws may now alias them

    const float sink = sinks[h];
#pragma unroll
    for (int reg = 0; reg < 4; ++reg) {
        const int qg = qs + w16 + quad*4 + reg;
        float mx = -1e30f;
#pragma unroll
        for (int jt = 0; jt < 12; ++jt) {
            int kg = qs - 128 + jt*16 + lm;
            float sv = S[jt][reg] * 0.125f;   // 1/sqrt(64)
            bool valid = (kg >= 0) && (kg <= qg) && (qg - kg <= 128);
            sv = valid ? sv : -1e30f;
            S[jt][reg] = sv;
            mx = fmaxf(mx, sv);
        }
#pragma unroll
        for (int off = 1; off < 16; off <<= 1) mx = fmaxf(mx, __shfl_xor(mx, off));
        float M = fmaxf(mx, sink);
        float sum = 0.f;
#pragma unroll
        for (int jt = 0; jt < 12; ++jt) {
            float e = __expf(S[jt][reg] - M);
            S[jt][reg] = e; sum += e;
        }
#pragma unroll
        for (int off = 1; off < 16; off <<= 1) sum += __shfl_xor(sum, off);
        float rden = 1.f / (sum + __expf(sink - M));
#pragma unroll
        for (int jt = 0; jt < 12; ++jt)
            Ws[(w16 + quad*4 + reg)*200 + jt*16 + lm] = (bf16_t)(S[jt][reg] * rden);
    }
    __syncthreads();

    // O = W V : each wave 16 queries x 64 dims
    f32x4 O[4];
#pragma unroll
    for (int nt = 0; nt < 4; ++nt) O[nt] = (f32x4){0.f, 0.f, 0.f, 0.f};
#pragma unroll
    for (int ks = 0; ks < 6; ++ks) {
        bf16x8 aw = *(const bf16x8*)&Ws[(w16 + lm)*200 + ks*32 + quad*8];
#pragma unroll
        for (int nt = 0; nt < 4; ++nt) {
            bf16x8 bv = *(const bf16x8*)&Vt[(nt*16 + lm)*200 + ks*32 + quad*8];
            O[nt] = mfma16(aw, bv, O[nt]);
        }
    }
#pragma unroll
    for (int nt = 0; nt < 4; ++nt)
#pragma unroll
        for (int reg = 0; reg < 4; ++reg)
            attnb[(size_t)(qs + w16 + quad*4 + reg)*HID + h*HDIM + nt*16 + lm] =
                (bf16_t)(O[nt][reg]);
}

// ---------------- launch ----------------
extern "C" void kernel_launch(void* const* d_in, const int* in_sizes, int n_in,
                              void* d_out, int out_size, void* d_ws, size_t ws_size,
                              hipStream_t stream) {
    (void)in_sizes; (void)n_in; (void)out_size; (void)ws_size;
    const float* x          = (const float*)d_in[0];
    const float* scale      = (const float*)d_in[1];
    const float* sinks      = (const float*)d_in[2];
    const float* qkv_kernel = (const float*)d_in[3];
    const float* qkv_bias   = (const float*)d_in[4];
    const float* out_kernel = (const float*)d_in[5];
    const float* out_bias   = (const float*)d_in[6];
    const float* cos_t      = (const float*)d_in[7];
    const float* sin_t      = (const float*)d_in[8];
    float* out = (float*)d_out;

    char* ws = (char*)d_ws;
    bf16_t* Wt_qkv = (bf16_t*)(ws);                       // [3072][2048] 12 MiB
    bf16_t* Wt_out = (bf16_t*)(ws + 12582912);            // [2048][2048]  8 MiB
    float*  qkv    = (float*) (ws + 20971520);            // [2048][3072] 24 MiB
    bf16_t* Qb     = (bf16_t*)(ws + 46137344);            // [T][32][64]   8 MiB
    bf16_t* Kb     = (bf16_t*)(ws + 54525952);            // [T][8][64]    2 MiB
    bf16_t* Vb     = (bf16_t*)(ws + 56623104);            // [T][8][64]    2 MiB
    bf16_t* normed = (bf16_t*)(ws + 58720256);            // [T][2048]     8 MiB
    bf16_t* attnb  = (bf16_t*)(ws + 58720256);            // aliases normed (dead after QKV GEMM)

    transpose_cast<<<dim3(QKVD/32, HID/32), 256, 0, stream>>>(qkv_kernel, Wt_qkv, HID, QKVD);
    transpose_cast<<<dim3(HID/32,  HID/32), 256, 0, stream>>>(out_kernel, Wt_out, HID, HID);
    rmsnorm_cast<<<T_SEQ, 256, 0, stream>>>(x, scale, normed);
    gemm_bt<0><<<dim3(QKVD/128, T_SEQ/128), 256, 0, stream>>>(normed, Wt_qkv, qkv_bias,
                                                              nullptr, qkv, T_SEQ, QKVD, HID);
    rope_split<<<T_SEQ, 256, 0, stream>>>(qkv, cos_t, sin_t, Qb, Kb, Vb);
    attn_kernel<<<dim3(T_SEQ/64, NHEAD), 256, 0, stream>>>(Qb, Kb, Vb, sinks, attnb);
    gemm_bt<1><<<dim3(HID/128, T_SEQ/128), 256, 0, stream>>>(attnb, Wt_out, out_bias,
                                                             x, out, T_SEQ, HID, HID);
}

// Round 2
// 255.050 us; speedup vs baseline: 1.0467x; 1.0467x over previous
//
#include <hip/hip_runtime.h>
#include <hip/hip_bf16.h>
#include <stdint.h>

typedef __bf16 bf16_t;
typedef __attribute__((ext_vector_type(8))) __bf16 bf16x8;
typedef __attribute__((ext_vector_type(4))) __bf16 bf16x4;
typedef __attribute__((ext_vector_type(4))) float f32x4;

static constexpr int T_SEQ = 2048;
static constexpr int HID   = 2048;
static constexpr int NHEAD = 32;
static constexpr int NKVH  = 8;
static constexpr int HDIM  = 64;
static constexpr int QKVD  = 3072;   // 64*(32+16)

__device__ inline f32x4 mfma16(bf16x8 a, bf16x8 b, f32x4 c) {
    return __builtin_amdgcn_mfma_f32_16x16x32_bf16(a, b, c, 0, 0, 0);
}

// async global->LDS DMA: lane i of the wave writes lds_base + i*16 bytes.
__device__ inline void load_lds16(const bf16_t* g, bf16_t* l) {
    __builtin_amdgcn_global_load_lds(
        (const __attribute__((address_space(1))) void*)g,
        (__attribute__((address_space(3))) void*)l, 16, 0, 0);
}

// ---------------- transpose + cast: in fp32 [K][N] -> out bf16 [N][K] ----------------
__global__ __launch_bounds__(256) void transpose_cast(const float* __restrict__ in,
                                                      bf16_t* __restrict__ out,
                                                      int K, int N) {
    __shared__ float tile[32][33];
    int tx = threadIdx.x & 31, ty = threadIdx.x >> 5;   // 32 x 8
    int bx = blockIdx.x, by = blockIdx.y;               // N/32, K/32
#pragma unroll
    for (int i = 0; i < 4; ++i)
        tile[ty + 8*i][tx] = in[(size_t)(by*32 + ty + 8*i)*N + bx*32 + tx];
    __syncthreads();
#pragma unroll
    for (int i = 0; i < 4; ++i)
        out[(size_t)(bx*32 + ty + 8*i)*K + by*32 + tx] = (bf16_t)tile[tx][ty + 8*i];
}

// ---------------- RMSNorm + cast to bf16 ----------------
__global__ __launch_bounds__(256) void rmsnorm_cast(const float* __restrict__ x,
                                                    const float* __restrict__ scale,
                                                    bf16_t* __restrict__ out) {
    int row = blockIdx.x;
    int tid = threadIdx.x;
    const float4* x4 = (const float4*)(x + (size_t)row * HID);
    const float4* s4 = (const float4*)scale;
    float4 v0 = x4[tid], v1 = x4[tid + 256];
    float ss = v0.x*v0.x + v0.y*v0.y + v0.z*v0.z + v0.w*v0.w
             + v1.x*v1.x + v1.y*v1.y + v1.z*v1.z + v1.w*v1.w;
#pragma unroll
    for (int off = 32; off > 0; off >>= 1) ss += __shfl_down(ss, off);
    __shared__ float wsum[4];
    if ((tid & 63) == 0) wsum[tid >> 6] = ss;
    __syncthreads();
    float total = wsum[0] + wsum[1] + wsum[2] + wsum[3];
    float inv = rsqrtf(total * (1.0f / HID) + 1e-5f);
    float4 sc0 = s4[tid], sc1 = s4[tid + 256];
    bf16_t* outr = out + (size_t)row * HID;
    bf16x4 o0, o1;
    o0.x = (bf16_t)(v0.x*inv*sc0.x); o0.y = (bf16_t)(v0.y*inv*sc0.y);
    o0.z = (bf16_t)(v0.z*inv*sc0.z); o0.w = (bf16_t)(v0.w*inv*sc0.w);
    o1.x = (bf16_t)(v1.x*inv*sc1.x); o1.y = (bf16_t)(v1.y*inv*sc1.y);
    o1.z = (bf16_t)(v1.z*inv*sc1.z); o1.w = (bf16_t)(v1.w*inv*sc1.w);
    *(bf16x4*)(outr + 4*tid)        = o0;
    *(bf16x4*)(outr + 1024 + 4*tid) = o1;
}

// ---------------- GEMM: C[M][N] = A[M][K](bf16) * Bt[N][K]^T(bf16) + bias (+resid) ----------------
// global_load_lds staging (width 16, no padding allowed) with XOR-swizzled layout:
// LDS chunk j (16 B) holds global chunk (r = j>>2, c = (j&3) ^ ((r>>1)&3)).
// Fragment read for (row R, quad q): offset = R*32 + ((q ^ ((R>>1)&3)) * 8) elements.
// Since R = base16 + lm, (R>>1)&3 == (lm>>1)&3. Conflict-free per 8-lane phase.
template <int RES>
__global__ __launch_bounds__(256) void gemm_bt(const bf16_t* __restrict__ A,
                                               const bf16_t* __restrict__ Bt,
                                               const float* __restrict__ bias,
                                               const float* __restrict__ resid,
                                               float* __restrict__ C,
                                               int M, int N, int K) {
    __shared__ __align__(16) bf16_t Asm[128 * 32];   // 8 KiB, dense 64 B rows
    __shared__ __align__(16) bf16_t Bsm[128 * 32];
    const int tid = threadIdx.x;
    const int bm = blockIdx.y * 128, bn = blockIdx.x * 128;
    const int lane = tid & 63, wave = tid >> 6;
    const int wm = (wave & 1) * 64, wn = (wave >> 1) * 64;
    const int lm = lane & 15, quad = lane >> 4;

    f32x4 acc[4][4];
#pragma unroll
    for (int i = 0; i < 4; ++i)
#pragma unroll
        for (int j = 0; j < 4; ++j) acc[i][j] = (f32x4){0.f, 0.f, 0.f, 0.f};

    // per-lane swizzled global source offsets for the two DMA instructions
    const int cid0 = wave * 64 + lane;          // chunk 0..255
    const int cid1 = cid0 + 256;                // chunk 256..511
    const int r0 = cid0 >> 2, c0 = (cid0 & 3) ^ ((r0 >> 1) & 3);
    const int r1 = cid1 >> 2, c1 = (cid1 & 3) ^ ((r1 >> 1) & 3);
    const bf16_t* Ab = A  + (size_t)bm * K;
    const bf16_t* Bb = Bt + (size_t)bn * K;
    const size_t ga0 = (size_t)r0 * K + c0 * 8;
    const size_t ga1 = (size_t)r1 * K + c1 * 8;
    bf16_t* lds0 = &Asm[wave * 512];            // chunk base (wave*64)*8 elems
    bf16_t* lds1 = &Asm[2048 + wave * 512];
    bf16_t* ldsB0 = &Bsm[wave * 512];
    bf16_t* ldsB1 = &Bsm[2048 + wave * 512];

    const int swzA = (quad ^ ((lm >> 1) & 3)) * 8;   // same for B

    for (int k0 = 0; k0 < K; k0 += 32) {
        load_lds16(Ab + ga0 + k0, lds0);
        load_lds16(Ab + ga1 + k0, lds1);
        load_lds16(Bb + ga0 + k0, ldsB0);
        load_lds16(Bb + ga1 + k0, ldsB1);
        __syncthreads();
        bf16x8 af[4], bfr[4];
#pragma unroll
        for (int i = 0; i < 4; ++i)
            af[i]  = *(const bf16x8*)&Asm[(wm + i*16 + lm)*32 + swzA];
#pragma unroll
        for (int j = 0; j < 4; ++j)
            bfr[j] = *(const bf16x8*)&Bsm[(wn + j*16 + lm)*32 + swzA];
#pragma unroll
        for (int i = 0; i < 4; ++i)
#pragma unroll
            for (int j = 0; j < 4; ++j) acc[i][j] = mfma16(af[i], bfr[j], acc[i][j]);
        __syncthreads();
    }

#pragma unroll
    for (int i = 0; i < 4; ++i) {
        int gr = bm + wm + i*16 + quad*4;
#pragma unroll
        for (int j = 0; j < 4; ++j) {
            int gc = bn + wn + j*16 + lm;
            float b = bias[gc];
#pragma unroll
            for (int r = 0; r < 4; ++r) {
                size_t idx = (size_t)(gr + r)*N + gc;
                float v = acc[i][j][r] + b;
                if (RES) v += resid[idx];
                C[idx] = v;
            }
        }
    }
}

// ---------------- RoPE (split-half) + cast, scatter into Q/K/V bf16 ----------------
__global__ __launch_bounds__(256) void rope_split(const float* __restrict__ qkv,
                                                  const float* __restrict__ cost,
                                                  const float* __restrict__ sint,
                                                  bf16_t* __restrict__ Qb,
                                                  bf16_t* __restrict__ Kb,
                                                  bf16_t* __restrict__ Vb) {
    int t = blockIdx.x;
    const float* row = qkv + (size_t)t * QKVD;
    const float* c = cost + (size_t)t * 32;
    const float* s = sint + (size_t)t * 32;
    for (int idx = threadIdx.x; idx < 1536; idx += 256) {
        int h = idx >> 5;     // 0..47 (32 q, 8 k, 8 v head-rows)
        int p = idx & 31;
        float x1 = row[h*64 + p], x2 = row[h*64 + p + 32];
        float o1, o2;
        if (h < 40) { float cc = c[p], ssn = s[p]; o1 = x1*cc - x2*ssn; o2 = x2*cc + x1*ssn; }
        else        { o1 = x1; o2 = x2; }
        bf16_t b1 = (bf16_t)o1, b2 = (bf16_t)o2;
        if (h < 32) {
            bf16_t* q = Qb + ((size_t)t*NHEAD + h)*HDIM;
            q[p] = b1; q[p + 32] = b2;
        } else if (h < 40) {
            bf16_t* k = Kb + ((size_t)t*NKVH + (h - 32))*HDIM;
            k[p] = b1; k[p + 32] = b2;
        } else {
            bf16_t* v = Vb + ((size_t)t*NKVH + (h - 40))*HDIM;
            v[p] = b1; v[p + 32] = b2;
        }
    }
}

// ---------------- attention: per (64-query tile, head); window fits one 192-key tile ----------------
__global__ __launch_bounds__(256) void attn_kernel(const bf16_t* __restrict__ Qb,
                                                   const bf16_t* __restrict__ Kb,
                                                   const bf16_t* __restrict__ Vb,
                                                   const float* __restrict__ sinks,
                                                   bf16_t* __restrict__ attnb) {
    // LDS plan (bytes): Qs[64][72] @0 (9216) ; Ks[192][72] @9216 (27648) ;
    //                   Vt[64][200] @36864 (25600) ; Ws[64][200] aliases @0 after sync.
    __shared__ __align__(16) char smem[62464];
    bf16_t* Qs = (bf16_t*)smem;
    bf16_t* Ks = (bf16_t*)(smem + 9216);
    bf16_t* Vt = (bf16_t*)(smem + 36864);
    bf16_t* Ws = (bf16_t*)smem;

    const int tid = threadIdx.x;
    const int qt = blockIdx.x, h = blockIdx.y;
    const int qs = qt * 64;
    const int nkv = h >> 2;

    // stage Q tile: 64 rows x 64 dims = 512 16B-chunks
#pragma unroll
    for (int it = 0; it < 2; ++it) {
        int cc = tid + it*256;
        int row = cc >> 3, off = (cc & 7) * 8;
        uint4 v = *(const uint4*)(Qb + ((size_t)(qs + row)*NHEAD + h)*HDIM + off);
        *(uint4*)&Qs[row*72 + off] = v;
    }
    // stage K (rows) and V (transposed) : 192 keys x 64 dims = 1536 chunks
#pragma unroll
    for (int it = 0; it < 6; ++it) {
        int cc = tid + it*256;
        int j = cc >> 3, off = (cc & 7) * 8;
        int kg = qs - 128 + j;
        uint4 kv = {0, 0, 0, 0}, vv = {0, 0, 0, 0};
        if (kg >= 0) {
            kv = *(const uint4*)(Kb + ((size_t)kg*NKVH + nkv)*HDIM + off);
            vv = *(const uint4*)(Vb + ((size_t)kg*NKVH + nkv)*HDIM + off);
        }
        *(uint4*)&Ks[j*72 + off] = kv;
        union { uint4 u; bf16_t e[8]; } uv; uv.u = vv;
#pragma unroll
        for (int r = 0; r < 8; ++r) Vt[(off + r)*200 + j] = uv.e[r];
    }
    __syncthreads();

    const int lane = tid & 63, wave = tid >> 6;
    const int lm = lane & 15, quad = lane >> 4;
    const int w16 = wave * 16;

    // S = Q K^T : each wave 16 queries x 192 keys
    f32x4 S[12];
#pragma unroll
    for (int jt = 0; jt < 12; ++jt) S[jt] = (f32x4){0.f, 0.f, 0.f, 0.f};
#pragma unroll
    for (int ks = 0; ks < 2; ++ks) {
        bf16x8 aq = *(const bf16x8*)&Qs[(w16 + lm)*72 + ks*32 + quad*8];
#pragma unroll
        for (int jt = 0; jt < 12; ++jt) {
            bf16x8 bk = *(const bf16x8*)&Ks[(jt*16 + lm)*72 + ks*32 + quad*8];
            S[jt] = mfma16(aq, bk, S[jt]);
        }
    }
    __syncthreads();   // all waves done reading Qs/Ks; Ws may now alias them

    const float sink = sinks[h];
#pragma unroll
    for (int reg = 0; reg < 4; ++reg) {
        const int qg = qs + w16 + quad*4 + reg;
        float mx = -1e30f;
#pragma unroll
        for (int jt = 0; jt < 12; ++jt) {
            int kg = qs - 128 + jt*16 + lm;
            float sv = S[jt][reg] * 0.125f;   // 1/sqrt(64)
            bool valid = (kg >= 0) && (kg <= qg) && (qg - kg <= 128);
            sv = valid ? sv : -1e30f;
            S[jt][reg] = sv;
            mx = fmaxf(mx, sv);
        }
#pragma unroll
        for (int off = 1; off < 16; off <<= 1) mx = fmaxf(mx, __shfl_xor(mx, off));
        float M = fmaxf(mx, sink);
        float sum = 0.f;
#pragma unroll
        for (int jt = 0; jt < 12; ++jt) {
            float e = __expf(S[jt][reg] - M);
            S[jt][reg] = e; sum += e;
        }
#pragma unroll
        for (int off = 1; off < 16; off <<= 1) sum += __shfl_xor(sum, off);
        float rden = 1.f / (sum + __expf(sink - M));
#pragma unroll
        for (int jt = 0; jt < 12; ++jt)
            Ws[(w16 + quad*4 + reg)*200 + jt*16 + lm] = (bf16_t)(S[jt][reg] * rden);
    }
    __syncthreads();

    // O = W V : each wave 16 queries x 64 dims
    f32x4 O[4];
#pragma unroll
    for (int nt = 0; nt < 4; ++nt) O[nt] = (f32x4){0.f, 0.f, 0.f, 0.f};
#pragma unroll
    for (int ks = 0; ks < 6; ++ks) {
        bf16x8 aw = *(const bf16x8*)&Ws[(w16 + lm)*200 + ks*32 + quad*8];
#pragma unroll
        for (int nt = 0; nt < 4; ++nt) {
            bf16x8 bv = *(const bf16x8*)&Vt[(nt*16 + lm)*200 + ks*32 + quad*8];
            O[nt] = mfma16(aw, bv, O[nt]);
        }
    }
#pragma unroll
    for (int nt = 0; nt < 4; ++nt)
#pragma unroll
        for (int reg = 0; reg < 4; ++reg)
            attnb[(size_t)(qs + w16 + quad*4 + reg)*HID + h*HDIM + nt*16 + lm] =
                (bf16_t)(O[nt][reg]);
}

// ---------------- launch ----------------
extern "C" void kernel_launch(void* const* d_in, const int* in_sizes, int n_in,
                              void* d_out, int out_size, void* d_ws, size_t ws_size,
                              hipStream_t stream) {
    (void)in_sizes; (void)n_in; (void)out_size; (void)ws_size;
    const float* x          = (const float*)d_in[0];
    const float* scale      = (const float*)d_in[1];
    const float* sinks      = (const float*)d_in[2];
    const float* qkv_kernel = (const float*)d_in[3];
    const float* qkv_bias   = (const float*)d_in[4];
    const float* out_kernel = (const float*)d_in[5];
    const float* out_bias   = (const float*)d_in[6];
    const float* cos_t      = (const float*)d_in[7];
    const float* sin_t      = (const float*)d_in[8];
    float* out = (float*)d_out;

    char* ws = (char*)d_ws;
    bf16_t* Wt_qkv = (bf16_t*)(ws);                       // [3072][2048] 12 MiB
    bf16_t* Wt_out = (bf16_t*)(ws + 12582912);            // [2048][2048]  8 MiB
    float*  qkv    = (float*) (ws + 20971520);            // [2048][3072] 24 MiB
    bf16_t* Qb     = (bf16_t*)(ws + 46137344);            // [T][32][64]   8 MiB
    bf16_t* Kb     = (bf16_t*)(ws + 54525952);            // [T][8][64]    2 MiB
    bf16_t* Vb     = (bf16_t*)(ws + 56623104);            // [T][8][64]    2 MiB
    bf16_t* normed = (bf16_t*)(ws + 58720256);            // [T][2048]     8 MiB
    bf16_t* attnb  = (bf16_t*)(ws + 58720256);            // aliases normed (dead after QKV GEMM)

    transpose_cast<<<dim3(QKVD/32, HID/32), 256, 0, stream>>>(qkv_kernel, Wt_qkv, HID, QKVD);
    transpose_cast<<<dim3(HID/32,  HID/32), 256, 0, stream>>>(out_kernel, Wt_out, HID, HID);
    rmsnorm_cast<<<T_SEQ, 256, 0, stream>>>(x, scale, normed);
    gemm_bt<0><<<dim3(QKVD/128, T_SEQ/128), 256, 0, stream>>>(normed, Wt_qkv, qkv_bias,
                                                              nullptr, qkv, T_SEQ, QKVD, HID);
    rope_split<<<T_SEQ, 256, 0, stream>>>(qkv, cos_t, sin_t, Qb, Kb, Vb);
    attn_kernel<<<dim3(T_SEQ/64, NHEAD), 256, 0, stream>>>(Qb, Kb, Vb, sinks, attnb);
    gemm_bt<1><<<dim3(HID/128, T_SEQ/128), 256, 0, stream>>>(attnb, Wt_out, out_bias,
                                                             x, out, T_SEQ, HID, HID);
}

// Round 3
// 235.008 us; speedup vs baseline: 1.1360x; 1.0853x over previous
//
#include <hip/hip_runtime.h>
#include <hip/hip_bf16.h>
#include <stdint.h>

typedef __bf16 bf16_t;
typedef __attribute__((ext_vector_type(8))) __bf16 bf16x8;
typedef __attribute__((ext_vector_type(4))) __bf16 bf16x4;
typedef __attribute__((ext_vector_type(4))) float f32x4;

static constexpr int T_SEQ = 2048;
static constexpr int HID   = 2048;
static constexpr int NHEAD = 32;
static constexpr int NKVH  = 8;
static constexpr int HDIM  = 64;
static constexpr int QKVD  = 3072;   // 64*(32+16)

__device__ inline f32x4 mfma16(bf16x8 a, bf16x8 b, f32x4 c) {
    return __builtin_amdgcn_mfma_f32_16x16x32_bf16(a, b, c, 0, 0, 0);
}

// async global->LDS DMA: lane i of the wave writes lds_base + i*16 bytes.
__device__ inline void load_lds16(const bf16_t* g, bf16_t* l) {
    __builtin_amdgcn_global_load_lds(
        (const __attribute__((address_space(1))) void*)g,
        (__attribute__((address_space(3))) void*)l, 16, 0, 0);
}

// ---------------- transpose + cast: in fp32 [K][N] -> out bf16 [N][K] ----------------
__global__ __launch_bounds__(256) void transpose_cast(const float* __restrict__ in,
                                                      bf16_t* __restrict__ out,
                                                      int K, int N) {
    __shared__ float tile[32][33];
    int tx = threadIdx.x & 31, ty = threadIdx.x >> 5;   // 32 x 8
    int bx = blockIdx.x, by = blockIdx.y;               // N/32, K/32
#pragma unroll
    for (int i = 0; i < 4; ++i)
        tile[ty + 8*i][tx] = in[(size_t)(by*32 + ty + 8*i)*N + bx*32 + tx];
    __syncthreads();
#pragma unroll
    for (int i = 0; i < 4; ++i)
        out[(size_t)(bx*32 + ty + 8*i)*K + by*32 + tx] = (bf16_t)tile[tx][ty + 8*i];
}

// ---------------- RMSNorm + cast to bf16 ----------------
__global__ __launch_bounds__(256) void rmsnorm_cast(const float* __restrict__ x,
                                                    const float* __restrict__ scale,
                                                    bf16_t* __restrict__ out) {
    int row = blockIdx.x;
    int tid = threadIdx.x;
    const float4* x4 = (const float4*)(x + (size_t)row * HID);
    const float4* s4 = (const float4*)scale;
    float4 v0 = x4[tid], v1 = x4[tid + 256];
    float ss = v0.x*v0.x + v0.y*v0.y + v0.z*v0.z + v0.w*v0.w
             + v1.x*v1.x + v1.y*v1.y + v1.z*v1.z + v1.w*v1.w;
#pragma unroll
    for (int off = 32; off > 0; off >>= 1) ss += __shfl_down(ss, off);
    __shared__ float wsum[4];
    if ((tid & 63) == 0) wsum[tid >> 6] = ss;
    __syncthreads();
    float total = wsum[0] + wsum[1] + wsum[2] + wsum[3];
    float inv = rsqrtf(total * (1.0f / HID) + 1e-5f);
    float4 sc0 = s4[tid], sc1 = s4[tid + 256];
    bf16_t* outr = out + (size_t)row * HID;
    bf16x4 o0, o1;
    o0.x = (bf16_t)(v0.x*inv*sc0.x); o0.y = (bf16_t)(v0.y*inv*sc0.y);
    o0.z = (bf16_t)(v0.z*inv*sc0.z); o0.w = (bf16_t)(v0.w*inv*sc0.w);
    o1.x = (bf16_t)(v1.x*inv*sc1.x); o1.y = (bf16_t)(v1.y*inv*sc1.y);
    o1.z = (bf16_t)(v1.z*inv*sc1.z); o1.w = (bf16_t)(v1.w*inv*sc1.w);
    *(bf16x4*)(outr + 4*tid)        = o0;
    *(bf16x4*)(outr + 1024 + 4*tid) = o1;
}

// ---------------- split-K GEMM: Cpart[z][M][N](bf16) = A[M][kb:kb+K/2] * Bt[N][kb:kb+K/2]^T ----
// global_load_lds staging (width 16) with XOR-swizzled layout (round-2 verified):
// LDS chunk j holds global chunk (r=j>>2, c=(j&3)^((r>>1)&3)); frag read offset
// (quad ^ ((lm>>1)&3))*8. Conflict-free staging writes and fragment reads.
__global__ __launch_bounds__(256) void gemm_splitk(const bf16_t* __restrict__ A,
                                                   const bf16_t* __restrict__ Bt,
                                                   bf16_t* __restrict__ Cpart,
                                                   int M, int N, int K) {
    __shared__ __align__(16) bf16_t Asm[128 * 32];   // 8 KiB, dense 64 B rows
    __shared__ __align__(16) bf16_t Bsm[128 * 32];
    const int tid = threadIdx.x;
    const int bm = blockIdx.y * 128, bn = blockIdx.x * 128;
    const int kh = K >> 1;
    const int kb = blockIdx.z * kh;                 // K-slice start
    const int lane = tid & 63, wave = tid >> 6;
    const int wm = (wave & 1) * 64, wn = (wave >> 1) * 64;
    const int lm = lane & 15, quad = lane >> 4;

    f32x4 acc[4][4];
#pragma unroll
    for (int i = 0; i < 4; ++i)
#pragma unroll
        for (int j = 0; j < 4; ++j) acc[i][j] = (f32x4){0.f, 0.f, 0.f, 0.f};

    const int cid0 = wave * 64 + lane;          // chunk 0..255
    const int cid1 = cid0 + 256;                // chunk 256..511
    const int r0 = cid0 >> 2, c0 = (cid0 & 3) ^ ((r0 >> 1) & 3);
    const int r1 = cid1 >> 2, c1 = (cid1 & 3) ^ ((r1 >> 1) & 3);
    const bf16_t* Ab = A  + (size_t)bm * K + kb;
    const bf16_t* Bb = Bt + (size_t)bn * K + kb;
    const size_t ga0 = (size_t)r0 * K + c0 * 8;
    const size_t ga1 = (size_t)r1 * K + c1 * 8;
    bf16_t* lds0 = &Asm[wave * 512];
    bf16_t* lds1 = &Asm[2048 + wave * 512];
    bf16_t* ldsB0 = &Bsm[wave * 512];
    bf16_t* ldsB1 = &Bsm[2048 + wave * 512];

    const int swz = (quad ^ ((lm >> 1) & 3)) * 8;

    for (int k0 = 0; k0 < kh; k0 += 32) {
        load_lds16(Ab + ga0 + k0, lds0);
        load_lds16(Ab + ga1 + k0, lds1);
        load_lds16(Bb + ga0 + k0, ldsB0);
        load_lds16(Bb + ga1 + k0, ldsB1);
        __syncthreads();
        bf16x8 af[4], bfr[4];
#pragma unroll
        for (int i = 0; i < 4; ++i)
            af[i]  = *(const bf16x8*)&Asm[(wm + i*16 + lm)*32 + swz];
#pragma unroll
        for (int j = 0; j < 4; ++j)
            bfr[j] = *(const bf16x8*)&Bsm[(wn + j*16 + lm)*32 + swz];
#pragma unroll
        for (int i = 0; i < 4; ++i)
#pragma unroll
            for (int j = 0; j < 4; ++j) acc[i][j] = mfma16(af[i], bfr[j], acc[i][j]);
        __syncthreads();
    }

    bf16_t* Cp = Cpart + (size_t)blockIdx.z * M * N;
#pragma unroll
    for (int i = 0; i < 4; ++i) {
        int gr = bm + wm + i*16 + quad*4;
#pragma unroll
        for (int j = 0; j < 4; ++j) {
            int gc = bn + wn + j*16 + lm;
#pragma unroll
            for (int r = 0; r < 4; ++r)
                Cp[(size_t)(gr + r)*N + gc] = (bf16_t)acc[i][j][r];
        }
    }
}

// ---------------- combine partials + bias + rope + cast, scatter into Q/K/V bf16 ----------------
__global__ __launch_bounds__(256) void rope_split(const bf16_t* __restrict__ qp0,
                                                  const bf16_t* __restrict__ qp1,
                                                  const float* __restrict__ qbias,
                                                  const float* __restrict__ cost,
                                                  const float* __restrict__ sint,
                                                  bf16_t* __restrict__ Qb,
                                                  bf16_t* __restrict__ Kb,
                                                  bf16_t* __restrict__ Vb) {
    int t = blockIdx.x;
    const bf16_t* row0 = qp0 + (size_t)t * QKVD;
    const bf16_t* row1 = qp1 + (size_t)t * QKVD;
    const float* c = cost + (size_t)t * 32;
    const float* s = sint + (size_t)t * 32;
    for (int idx = threadIdx.x; idx < 1536; idx += 256) {
        int h = idx >> 5;     // 0..47 (32 q, 8 k, 8 v head-rows)
        int p = idx & 31;
        float x1 = (float)row0[h*64 + p]      + (float)row1[h*64 + p]      + qbias[h*64 + p];
        float x2 = (float)row0[h*64 + p + 32] + (float)row1[h*64 + p + 32] + qbias[h*64 + p + 32];
        float o1, o2;
        if (h < 40) { float cc = c[p], ssn = s[p]; o1 = x1*cc - x2*ssn; o2 = x2*cc + x1*ssn; }
        else        { o1 = x1; o2 = x2; }
        bf16_t b1 = (bf16_t)o1, b2 = (bf16_t)o2;
        if (h < 32) {
            bf16_t* q = Qb + ((size_t)t*NHEAD + h)*HDIM;
            q[p] = b1; q[p + 32] = b2;
        } else if (h < 40) {
            bf16_t* k = Kb + ((size_t)t*NKVH + (h - 32))*HDIM;
            k[p] = b1; k[p + 32] = b2;
        } else {
            bf16_t* v = Vb + ((size_t)t*NKVH + (h - 40))*HDIM;
            v[p] = b1; v[p + 32] = b2;
        }
    }
}

// ---------------- combine out-proj partials + bias + residual ----------------
__global__ __launch_bounds__(256) void combine_out(const bf16_t* __restrict__ p0,
                                                   const bf16_t* __restrict__ p1,
                                                   const float* __restrict__ bias,
                                                   const float* __restrict__ x,
                                                   float* __restrict__ out) {
    const int n4 = T_SEQ * HID / 4;
    for (int i4 = blockIdx.x * 256 + threadIdx.x; i4 < n4; i4 += gridDim.x * 256) {
        bf16x4 a = *(const bf16x4*)(p0 + (size_t)i4 * 4);
        bf16x4 b = *(const bf16x4*)(p1 + (size_t)i4 * 4);
        float4 xv = *(const float4*)(x + (size_t)i4 * 4);
        int col4 = (i4 * 4) & (HID - 1);
        float4 bi = *(const float4*)(bias + col4);
        float4 o;
        o.x = (float)a.x + (float)b.x + bi.x + xv.x;
        o.y = (float)a.y + (float)b.y + bi.y + xv.y;
        o.z = (float)a.z + (float)b.z + bi.z + xv.z;
        o.w = (float)a.w + (float)b.w + bi.w + xv.w;
        *(float4*)(out + (size_t)i4 * 4) = o;
    }
}

// ---------------- attention: per (64-query tile, head); window fits one 192-key tile ----------------
__global__ __launch_bounds__(256) void attn_kernel(const bf16_t* __restrict__ Qb,
                                                   const bf16_t* __restrict__ Kb,
                                                   const bf16_t* __restrict__ Vb,
                                                   const float* __restrict__ sinks,
                                                   bf16_t* __restrict__ attnb) {
    __shared__ __align__(16) char smem[62464];
    bf16_t* Qs = (bf16_t*)smem;
    bf16_t* Ks = (bf16_t*)(smem + 9216);
    bf16_t* Vt = (bf16_t*)(smem + 36864);
    bf16_t* Ws = (bf16_t*)smem;

    const int tid = threadIdx.x;
    const int qt = blockIdx.x, h = blockIdx.y;
    const int qs = qt * 64;
    const int nkv = h >> 2;

#pragma unroll
    for (int it = 0; it < 2; ++it) {
        int cc = tid + it*256;
        int row = cc >> 3, off = (cc & 7) * 8;
        uint4 v = *(const uint4*)(Qb + ((size_t)(qs + row)*NHEAD + h)*HDIM + off);
        *(uint4*)&Qs[row*72 + off] = v;
    }
#pragma unroll
    for (int it = 0; it < 6; ++it) {
        int cc = tid + it*256;
        int j = cc >> 3, off = (cc & 7) * 8;
        int kg = qs - 128 + j;
        uint4 kv = {0, 0, 0, 0}, vv = {0, 0, 0, 0};
        if (kg >= 0) {
            kv = *(const uint4*)(Kb + ((size_t)kg*NKVH + nkv)*HDIM + off);
            vv = *(const uint4*)(Vb + ((size_t)kg*NKVH + nkv)*HDIM + off);
        }
        *(uint4*)&Ks[j*72 + off] = kv;
        union { uint4 u; bf16_t e[8]; } uv; uv.u = vv;
#pragma unroll
        for (int r = 0; r < 8; ++r) Vt[(off + r)*200 + j] = uv.e[r];
    }
    __syncthreads();

    const int lane = tid & 63, wave = tid >> 6;
    const int lm = lane & 15, quad = lane >> 4;
    const int w16 = wave * 16;

    f32x4 S[12];
#pragma unroll
    for (int jt = 0; jt < 12; ++jt) S[jt] = (f32x4){0.f, 0.f, 0.f, 0.f};
#pragma unroll
    for (int ks = 0; ks < 2; ++ks) {
        bf16x8 aq = *(const bf16x8*)&Qs[(w16 + lm)*72 + ks*32 + quad*8];
#pragma unroll
        for (int jt = 0; jt < 12; ++jt) {
            bf16x8 bk = *(const bf16x8*)&Ks[(jt*16 + lm)*72 + ks*32 + quad*8];
            S[jt] = mfma16(aq, bk, S[jt]);
        }
    }
    __syncthreads();

    const float sink = sinks[h];
#pragma unroll
    for (int reg = 0; reg < 4; ++reg) {
        const int qg = qs + w16 + quad*4 + reg;
        float mx = -1e30f;
#pragma unroll
        for (int jt = 0; jt < 12; ++jt) {
            int kg = qs - 128 + jt*16 + lm;
            float sv = S[jt][reg] * 0.125f;
            bool valid = (kg >= 0) && (kg <= qg) && (qg - kg <= 128);
            sv = valid ? sv : -1e30f;
            S[jt][reg] = sv;
            mx = fmaxf(mx, sv);
        }
#pragma unroll
        for (int off = 1; off < 16; off <<= 1) mx = fmaxf(mx, __shfl_xor(mx, off));
        float M = fmaxf(mx, sink);
        float sum = 0.f;
#pragma unroll
        for (int jt = 0; jt < 12; ++jt) {
            float e = __expf(S[jt][reg] - M);
            S[jt][reg] = e; sum += e;
        }
#pragma unroll
        for (int off = 1; off < 16; off <<= 1) sum += __shfl_xor(sum, off);
        float rden = 1.f / (sum + __expf(sink - M));
#pragma unroll
        for (int jt = 0; jt < 12; ++jt)
            Ws[(w16 + quad*4 + reg)*200 + jt*16 + lm] = (bf16_t)(S[jt][reg] * rden);
    }
    __syncthreads();

    f32x4 O[4];
#pragma unroll
    for (int nt = 0; nt < 4; ++nt) O[nt] = (f32x4){0.f, 0.f, 0.f, 0.f};
#pragma unroll
    for (int ks = 0; ks < 6; ++ks) {
        bf16x8 aw = *(const bf16x8*)&Ws[(w16 + lm)*200 + ks*32 + quad*8];
#pragma unroll
        for (int nt = 0; nt < 4; ++nt) {
            bf16x8 bv = *(const bf16x8*)&Vt[(nt*16 + lm)*200 + ks*32 + quad*8];
            O[nt] = mfma16(aw, bv, O[nt]);
        }
    }
#pragma unroll
    for (int nt = 0; nt < 4; ++nt)
#pragma unroll
        for (int reg = 0; reg < 4; ++reg)
            attnb[(size_t)(qs + w16 + quad*4 + reg)*HID + h*HDIM + nt*16 + lm] =
                (bf16_t)(O[nt][reg]);
}

// ---------------- launch ----------------
extern "C" void kernel_launch(void* const* d_in, const int* in_sizes, int n_in,
                              void* d_out, int out_size, void* d_ws, size_t ws_size,
                              hipStream_t stream) {
    (void)in_sizes; (void)n_in; (void)out_size; (void)ws_size;
    const float* x          = (const float*)d_in[0];
    const float* scale      = (const float*)d_in[1];
    const float* sinks      = (const float*)d_in[2];
    const float* qkv_kernel = (const float*)d_in[3];
    const float* qkv_bias   = (const float*)d_in[4];
    const float* out_kernel = (const float*)d_in[5];
    const float* out_bias   = (const float*)d_in[6];
    const float* cos_t      = (const float*)d_in[7];
    const float* sin_t      = (const float*)d_in[8];
    float* out = (float*)d_out;

    // ws plan (64 MiB total, aliasing by liveness):
    //   [ 0, 8)   Wt_out  [2048][2048] bf16           (alive all run)
    //   [ 8,20)   Wt_qkv  [3072][2048] bf16           (dead after QKV GEMM)
    //   [ 8,16)   attnb   [T][2048] bf16              (aliases Wt_qkv; written by attn)
    //   [20,28)   normed  [T][2048] bf16              (dead after QKV GEMM)
    //   [28,52)   qkvp0/p1 [2][T][3072] bf16          (dead after rope)
    //   [28,44)   outp0/p1 [2][T][2048] bf16          (aliases qkvp; written by out GEMM)
    //   [52,64)   Qb/Kb/Vb bf16
    char* ws = (char*)d_ws;
    const size_t MiB = 1048576;
    bf16_t* Wt_out = (bf16_t*)(ws);
    bf16_t* Wt_qkv = (bf16_t*)(ws + 8*MiB);
    bf16_t* attnb  = (bf16_t*)(ws + 8*MiB);
    bf16_t* normed = (bf16_t*)(ws + 20*MiB);
    bf16_t* qkvp   = (bf16_t*)(ws + 28*MiB);   // two slices of 12 MiB
    bf16_t* outp   = (bf16_t*)(ws + 28*MiB);   // two slices of 8 MiB
    bf16_t* Qb     = (bf16_t*)(ws + 52*MiB);
    bf16_t* Kb     = (bf16_t*)(ws + 60*MiB);
    bf16_t* Vb     = (bf16_t*)(ws + 62*MiB);

    transpose_cast<<<dim3(QKVD/32, HID/32), 256, 0, stream>>>(qkv_kernel, Wt_qkv, HID, QKVD);
    transpose_cast<<<dim3(HID/32,  HID/32), 256, 0, stream>>>(out_kernel, Wt_out, HID, HID);
    rmsnorm_cast<<<T_SEQ, 256, 0, stream>>>(x, scale, normed);
    gemm_splitk<<<dim3(QKVD/128, T_SEQ/128, 2), 256, 0, stream>>>(normed, Wt_qkv, qkvp,
                                                                  T_SEQ, QKVD, HID);
    rope_split<<<T_SEQ, 256, 0, stream>>>(qkvp, qkvp + (size_t)T_SEQ*QKVD, qkv_bias,
                                          cos_t, sin_t, Qb, Kb, Vb);
    attn_kernel<<<dim3(T_SEQ/64, NHEAD), 256, 0, stream>>>(Qb, Kb, Vb, sinks, attnb);
    gemm_splitk<<<dim3(HID/128, T_SEQ/128, 2), 256, 0, stream>>>(attnb, Wt_out, outp,
                                                                 T_SEQ, HID, HID);
    combine_out<<<2048, 256, 0, stream>>>(outp, outp + (size_t)T_SEQ*HID, out_bias, x, out);
}